// Round 1
// baseline (1687.318 us; speedup 1.0000x reference)
//
#include <hip/hip_runtime.h>
#include <hip/hip_bf16.h>

#define B_     8
#define N_     1025
#define C_     3200
#define H_     25
#define D_     128
#define NQKV   (3 * C_)      // 9600
#define M_REAL (B_ * N_)     // 8200
#define M_PAD  8320          // 65 * 128

typedef __bf16 bf16x8 __attribute__((ext_vector_type(8)));
typedef short  short8 __attribute__((ext_vector_type(8)));
typedef float  f32x4  __attribute__((ext_vector_type(4)));

__device__ __forceinline__ unsigned short f2bf(float f) {
    unsigned u = __builtin_bit_cast(unsigned, f);
    u += 0x7FFFu + ((u >> 16) & 1u);          // RNE; inputs are finite
    return (unsigned short)(u >> 16);
}
__device__ __forceinline__ float bf2f(unsigned short u) {
    unsigned v = ((unsigned)u) << 16;
    return __builtin_bit_cast(float, v);
}
__device__ __forceinline__ void gload_lds16(const unsigned short* g, void* lds) {
    __builtin_amdgcn_global_load_lds(
        (const __attribute__((address_space(1))) void*)g,
        (__attribute__((address_space(3))) void*)lds, 16, 0, 0);
}

// ---------------- fp32 -> bf16 convert, with zero tail padding ----------------
__global__ __launch_bounds__(256) void convert_pad(const float* __restrict__ src,
                                                   unsigned short* __restrict__ dst,
                                                   long n_src, long n_tot) {
    long e = ((long)blockIdx.x * 256 + threadIdx.x) * 4;
    if (e >= n_tot) return;
    ushort4 o;
    if (e < n_src) {
        float4 v = *reinterpret_cast<const float4*>(src + e);
        o.x = f2bf(v.x); o.y = f2bf(v.y); o.z = f2bf(v.z); o.w = f2bf(v.w);
    } else {
        o.x = o.y = o.z = o.w = 0;
    }
    *reinterpret_cast<ushort4*>(dst + e) = o;
}

// ---------------- RMSNorm (full 3200-axis) applied in place to q / k ----------------
__global__ __launch_bounds__(256) void rmsnorm_qk(unsigned short* __restrict__ qkv,
                                                  const float* __restrict__ qw,
                                                  const float* __restrict__ kw) {
    const int row = blockIdx.x;          // 0..8199
    const int seg = blockIdx.y;          // 0=q, 1=k
    unsigned short* p = qkv + (long)row * NQKV + seg * C_;
    const float* w = seg ? kw : qw;
    const int t = threadIdx.x;
    const bool has2 = t < (400 - 256);   // 3200 elems = 400 x short8

    short8 v0 = reinterpret_cast<const short8*>(p)[t];
    short8 v1;
    if (has2) v1 = reinterpret_cast<const short8*>(p)[t + 256];

    float s = 0.f;
#pragma unroll
    for (int j = 0; j < 8; ++j) { float f = bf2f((unsigned short)v0[j]); s += f * f; }
    if (has2) {
#pragma unroll
        for (int j = 0; j < 8; ++j) { float f = bf2f((unsigned short)v1[j]); s += f * f; }
    }
#pragma unroll
    for (int m = 32; m; m >>= 1) s += __shfl_xor(s, m);
    __shared__ float red[4];
    if ((t & 63) == 0) red[t >> 6] = s;
    __syncthreads();
    float tot = red[0] + red[1] + red[2] + red[3];
    float scale = rsqrtf(tot * (1.f / C_) + 1e-6f);

#pragma unroll
    for (int j = 0; j < 8; ++j) {
        float f = bf2f((unsigned short)v0[j]) * scale * w[t * 8 + j];
        v0[j] = (short)f2bf(f);
    }
    reinterpret_cast<short8*>(p)[t] = v0;
    if (has2) {
#pragma unroll
        for (int j = 0; j < 8; ++j) {
            float f = bf2f((unsigned short)v1[j]) * scale * w[(t + 256) * 8 + j];
            v1[j] = (short)f2bf(f);
        }
        reinterpret_cast<short8*>(p)[t + 256] = v1;
    }
}

// ---------------- NT GEMM: C = A(MxK) * B(NxK)^T, 128x128 tile, BK=32 (m97 structure) ----------------
template <int BF16OUT>
__global__ __launch_bounds__(256) void gemm_bt(const unsigned short* __restrict__ A,
                                               const unsigned short* __restrict__ Bm,
                                               unsigned short* __restrict__ Cb,
                                               float* __restrict__ Cf,
                                               const float* __restrict__ bias,
                                               int M, int N, int K, int MStore) {
    const int t = threadIdx.x;
    const int w = t >> 6, l = t & 63;
    const int lq = l & 15, lh = l >> 4;
    const int m0 = blockIdx.y * 128, n0 = blockIdx.x * 128;
    const int wr = w >> 1, wc = w & 1;

    __shared__ unsigned short sA[128 * 32];
    __shared__ unsigned short sB[128 * 32];

    const f32x4 fz = {0.f, 0.f, 0.f, 0.f};
    f32x4 acc[4][4];
#pragma unroll
    for (int i = 0; i < 4; ++i)
#pragma unroll
        for (int j = 0; j < 4; ++j) acc[i][j] = fz;

    const unsigned short* Abase = A + (long)m0 * K;
    const unsigned short* Bbase = Bm + (long)n0 * K;

    for (int k0 = 0; k0 < K; k0 += 32) {
        __syncthreads();
#pragma unroll
        for (int i = 0; i < 2; ++i) {
            int c = i * 256 + t;
            int row = c >> 2, slot = c & 3;         // 4 x 16B per 64B row
            gload_lds16(Abase + (long)row * K + k0 + slot * 8, (char*)sA + c * 16);
            gload_lds16(Bbase + (long)row * K + k0 + slot * 8, (char*)sB + c * 16);
        }
        __syncthreads();

        bf16x8 av[4], bv[4];
#pragma unroll
        for (int i = 0; i < 4; ++i) {
            int row = wr * 64 + i * 16 + lq;
            av[i] = *reinterpret_cast<const bf16x8*>(sA + row * 32 + lh * 8);
        }
#pragma unroll
        for (int j = 0; j < 4; ++j) {
            int row = wc * 64 + j * 16 + lq;
            bv[j] = *reinterpret_cast<const bf16x8*>(sB + row * 32 + lh * 8);
        }
#pragma unroll
        for (int i = 0; i < 4; ++i)
#pragma unroll
            for (int j = 0; j < 4; ++j)
                acc[i][j] = __builtin_amdgcn_mfma_f32_16x16x32_bf16(av[i], bv[j], acc[i][j], 0, 0, 0);
    }

#pragma unroll
    for (int i = 0; i < 4; ++i) {
#pragma unroll
        for (int r = 0; r < 4; ++r) {
            int grow = m0 + wr * 64 + i * 16 + lh * 4 + r;   // C/D: row=(l>>4)*4+reg
            if (grow >= MStore) continue;
#pragma unroll
            for (int j = 0; j < 4; ++j) {
                int gcol = n0 + wc * 64 + j * 16 + lq;       // C/D: col=lane&15
                float v = acc[i][j][r];
                if (BF16OUT)
                    Cb[(long)grow * N + gcol] = f2bf(v);
                else
                    Cf[(long)grow * N + gcol] = v + bias[gcol];
            }
        }
    }
}

// ---------------- flash attention: 64 q-rows/block (4 waves x 16), KV tile = 32 ----------------
__global__ __launch_bounds__(256) void attn_fwd(const unsigned short* __restrict__ qkv,
                                                unsigned short* __restrict__ outb) {
    const int qt = blockIdx.x, h = blockIdx.y, b = blockIdx.z;
    const int t = threadIdx.x, w = t >> 6, l = t & 63;
    const int lq = l & 15, lh = l >> 4;

    __shared__ unsigned short sK[32 * 128];     // [key][d], 16B slots XOR-swizzled via source
    __shared__ unsigned short sV[128 * 32];     // [d][key], slot-swizzled
    __shared__ unsigned short sP[4][16 * 32];   // per-wave P tile

    const int q0 = qt * 64 + w * 16;
    int qrow = q0 + lq; if (qrow > N_ - 1) qrow = N_ - 1;   // clamp; rows >= N_ never stored
    const unsigned short* qptr = qkv + (long)(b * N_ + qrow) * NQKV + h * D_;
    bf16x8 qf[4];
#pragma unroll
    for (int ds = 0; ds < 4; ++ds)
        qf[ds] = *reinterpret_cast<const bf16x8*>(qptr + ds * 32 + lh * 8);

    const f32x4 fz = {0.f, 0.f, 0.f, 0.f};
    f32x4 o[8];
#pragma unroll
    for (int nf = 0; nf < 8; ++nf) o[nf] = fz;
    float mreg[4] = {-1e30f, -1e30f, -1e30f, -1e30f};
    float lreg[4] = {0.f, 0.f, 0.f, 0.f};
    const float scale = 0.08838834764831845f;   // 1/sqrt(128)

    unsigned short* sPw = sP[w];

    for (int kt = 0; kt < 33; ++kt) {
        const int kb0 = kt * 32;
        __syncthreads();
        // stage K: linear LDS dest, swizzle applied to global source slot
#pragma unroll
        for (int i = 0; i < 2; ++i) {
            int c = i * 256 + t;
            int krow = c >> 4, slot = c & 15;
            int key = kb0 + krow; if (key > N_ - 1) key = N_ - 1;
            int sg = slot ^ (krow & 7);
            gload_lds16(qkv + (long)(b * N_ + key) * NQKV + C_ + h * D_ + sg * 8,
                        (char*)sK + c * 16);
        }
        // stage V transposed (reg round-trip), slot-XOR swizzle on writes
        {
            int kk = t >> 3, dblk = t & 7;
            int key = kb0 + kk; if (key > N_ - 1) key = N_ - 1;
            const unsigned short* vsrc = qkv + (long)(b * N_ + key) * NQKV + 2 * C_ + h * D_ + dblk * 16;
            short8 v0 = *reinterpret_cast<const short8*>(vsrc);
            short8 v1 = *reinterpret_cast<const short8*>(vsrc + 8);
#pragma unroll
            for (int j = 0; j < 8; ++j) {
                int d0 = dblk * 16 + j, d1 = d0 + 8;
                sV[d0 * 32 + ((((kk >> 3) ^ (d0 & 3))) << 3) + (kk & 7)] = (unsigned short)v0[j];
                sV[d1 * 32 + ((((kk >> 3) ^ (d1 & 3))) << 3) + (kk & 7)] = (unsigned short)v1[j];
            }
        }
        __syncthreads();

        // S = Q K^T  (16 q-rows x 32 keys per wave)
        f32x4 s0 = fz, s1 = fz;
#pragma unroll
        for (int ds = 0; ds < 4; ++ds) {
            int sl0 = (ds * 4 + lh) ^ (lq & 7);
            bf16x8 k0 = *reinterpret_cast<const bf16x8*>(sK + lq * 128 + sl0 * 8);
            s0 = __builtin_amdgcn_mfma_f32_16x16x32_bf16(qf[ds], k0, s0, 0, 0, 0);
            int kk1 = 16 + lq;
            int sl1 = (ds * 4 + lh) ^ (kk1 & 7);
            bf16x8 k1 = *reinterpret_cast<const bf16x8*>(sK + kk1 * 128 + sl1 * 8);
            s1 = __builtin_amdgcn_mfma_f32_16x16x32_bf16(qf[ds], k1, s1, 0, 0, 0);
        }
        const bool va0 = (kb0 + lq) < N_;
        const bool va1 = (kb0 + 16 + lq) < N_;
#pragma unroll
        for (int r = 0; r < 4; ++r) {
            s0[r] = va0 ? s0[r] * scale : -1e30f;
            s1[r] = va1 ? s1[r] * scale : -1e30f;
        }
        // online softmax per q-row (rows = lh*4+r, cols across the 16-lane group)
#pragma unroll
        for (int r = 0; r < 4; ++r) {
            float mx = fmaxf(s0[r], s1[r]);
#pragma unroll
            for (int msk = 1; msk < 16; msk <<= 1) mx = fmaxf(mx, __shfl_xor(mx, msk));
            float mnew = fmaxf(mreg[r], mx);
            float corr = __expf(mreg[r] - mnew);
            float p0 = __expf(s0[r] - mnew);
            float p1 = __expf(s1[r] - mnew);
            float rs = p0 + p1;
#pragma unroll
            for (int msk = 1; msk < 16; msk <<= 1) rs += __shfl_xor(rs, msk);
            lreg[r] = lreg[r] * corr + rs;
            mreg[r] = mnew;
#pragma unroll
            for (int nf = 0; nf < 8; ++nf) o[nf][r] *= corr;
            int prow = lh * 4 + r;
            int c1 = 16 + lq;
            sPw[prow * 32 + ((((lq >> 3) ^ (prow & 3))) << 3) + (lq & 7)] = f2bf(p0);
            sPw[prow * 32 + ((((c1 >> 3) ^ (prow & 3))) << 3) + (c1 & 7)] = f2bf(p1);
        }
        // PV: o(16x128) += P(16x32) * V(32x128)
        bf16x8 pa = *reinterpret_cast<const bf16x8*>(sPw + lq * 32 + ((lh ^ (lq & 3)) << 3));
#pragma unroll
        for (int nf = 0; nf < 8; ++nf) {
            int d = nf * 16 + lq;
            bf16x8 vf = *reinterpret_cast<const bf16x8*>(sV + d * 32 + ((lh ^ (d & 3)) << 3));
            o[nf] = __builtin_amdgcn_mfma_f32_16x16x32_bf16(pa, vf, o[nf], 0, 0, 0);
        }
    }

#pragma unroll
    for (int r = 0; r < 4; ++r) {
        int qr = q0 + lh * 4 + r;
        if (qr >= N_) continue;
        float inv = 1.f / lreg[r];
        unsigned short* dst = outb + (long)(b * N_ + qr) * C_ + h * D_;
#pragma unroll
        for (int nf = 0; nf < 8; ++nf)
            dst[nf * 16 + lq] = f2bf(o[nf][r] * inv);
    }
}

extern "C" void kernel_launch(void* const* d_in, const int* in_sizes, int n_in,
                              void* d_out, int out_size, void* d_ws, size_t ws_size,
                              hipStream_t stream) {
    (void)in_sizes; (void)n_in; (void)out_size; (void)ws_size;
    const float* x   = (const float*)d_in[0];
    const float* wq  = (const float*)d_in[1];
    const float* qnw = (const float*)d_in[2];
    const float* knw = (const float*)d_in[3];
    const float* wp  = (const float*)d_in[4];
    const float* bp  = (const float*)d_in[5];
    float* out = (float*)d_out;

    // workspace layout (bf16 buffers), total ~348 MB
    unsigned short* xb    = (unsigned short*)d_ws;                 // M_PAD x C
    unsigned short* wqb   = xb   + (size_t)M_PAD * C_;             // NQKV x C
    unsigned short* wpb   = wqb  + (size_t)NQKV * C_;              // C x C
    unsigned short* qkvb  = wpb  + (size_t)C_ * C_;                // M_PAD x NQKV
    unsigned short* attnb = qkvb + (size_t)M_PAD * NQKV;           // M_PAD x C

    auto cvt = [&](const float* s, unsigned short* d, long nsrc, long ntot) {
        int blocks = (int)((ntot / 4 + 255) / 256);
        convert_pad<<<blocks, 256, 0, stream>>>(s, d, nsrc, ntot);
    };
    cvt(x,  xb,  (long)M_REAL * C_, (long)M_PAD * C_);
    cvt(wq, wqb, (long)NQKV * C_,   (long)NQKV * C_);
    cvt(wp, wpb, (long)C_ * C_,     (long)C_ * C_);
    cvt(x, attnb + (size_t)M_REAL * C_, 0, (long)(M_PAD - M_REAL) * C_);  // zero pad rows

    gemm_bt<1><<<dim3(NQKV / 128, M_PAD / 128), 256, 0, stream>>>(
        xb, wqb, qkvb, nullptr, nullptr, M_PAD, NQKV, C_, M_PAD);

    rmsnorm_qk<<<dim3(M_REAL, 2), 256, 0, stream>>>(qkvb, qnw, knw);

    attn_fwd<<<dim3(17, H_, B_), 256, 0, stream>>>(qkvb, attnb);

    gemm_bt<0><<<dim3(C_ / 128, M_PAD / 128), 256, 0, stream>>>(
        attnb, wpb, nullptr, out, bp, M_PAD, C_, C_, M_REAL);
}

// Round 2
// 1685.747 us; speedup vs baseline: 1.0009x; 1.0009x over previous
//
#include <hip/hip_runtime.h>
#include <hip/hip_bf16.h>

#define B_     8
#define N_     1025
#define C_     3200
#define H_     25
#define D_     128
#define NQKV   (3 * C_)      // 9600
#define M_REAL (B_ * N_)     // 8200
#define M_PAD  8320          // 65 * 128

typedef __bf16 bf16x8 __attribute__((ext_vector_type(8)));
typedef short  short8 __attribute__((ext_vector_type(8)));
typedef float  f32x4  __attribute__((ext_vector_type(4)));

__device__ __forceinline__ unsigned short f2bf(float f) {
    unsigned u = __builtin_bit_cast(unsigned, f);
    u += 0x7FFFu + ((u >> 16) & 1u);          // RNE; inputs are finite
    return (unsigned short)(u >> 16);
}
__device__ __forceinline__ float bf2f(unsigned short u) {
    unsigned v = ((unsigned)u) << 16;
    return __builtin_bit_cast(float, v);
}
__device__ __forceinline__ void gload_lds16(const unsigned short* g, void* lds) {
    __builtin_amdgcn_global_load_lds(
        (const __attribute__((address_space(1))) void*)g,
        (__attribute__((address_space(3))) void*)lds, 16, 0, 0);
}

// ---------------- fp32 -> bf16 convert, with zero tail padding ----------------
__global__ __launch_bounds__(256) void convert_pad(const float* __restrict__ src,
                                                   unsigned short* __restrict__ dst,
                                                   long n_src, long n_tot) {
    long e = ((long)blockIdx.x * 256 + threadIdx.x) * 4;
    if (e >= n_tot) return;
    ushort4 o;
    if (e < n_src) {
        float4 v = *reinterpret_cast<const float4*>(src + e);
        o.x = f2bf(v.x); o.y = f2bf(v.y); o.z = f2bf(v.z); o.w = f2bf(v.w);
    } else {
        o.x = o.y = o.z = o.w = 0;
    }
    *reinterpret_cast<ushort4*>(dst + e) = o;
}

// ---------------- RMSNorm (full 3200-axis) applied in place to q / k ----------------
__global__ __launch_bounds__(256) void rmsnorm_qk(unsigned short* __restrict__ qkv,
                                                  const float* __restrict__ qw,
                                                  const float* __restrict__ kw) {
    const int row = blockIdx.x;          // 0..8199
    const int seg = blockIdx.y;          // 0=q, 1=k
    unsigned short* p = qkv + (long)row * NQKV + seg * C_;
    const float* w = seg ? kw : qw;
    const int t = threadIdx.x;
    const bool has2 = t < (400 - 256);   // 3200 elems = 400 x short8

    short8 v0 = reinterpret_cast<const short8*>(p)[t];
    short8 v1;
    if (has2) v1 = reinterpret_cast<const short8*>(p)[t + 256];

    float s = 0.f;
#pragma unroll
    for (int j = 0; j < 8; ++j) { float f = bf2f((unsigned short)v0[j]); s += f * f; }
    if (has2) {
#pragma unroll
        for (int j = 0; j < 8; ++j) { float f = bf2f((unsigned short)v1[j]); s += f * f; }
    }
#pragma unroll
    for (int m = 32; m; m >>= 1) s += __shfl_xor(s, m);
    __shared__ float red[4];
    if ((t & 63) == 0) red[t >> 6] = s;
    __syncthreads();
    float tot = red[0] + red[1] + red[2] + red[3];
    float scale = rsqrtf(tot * (1.f / C_) + 1e-6f);

#pragma unroll
    for (int j = 0; j < 8; ++j) {
        float f = bf2f((unsigned short)v0[j]) * scale * w[t * 8 + j];
        v0[j] = (short)f2bf(f);
    }
    reinterpret_cast<short8*>(p)[t] = v0;
    if (has2) {
#pragma unroll
        for (int j = 0; j < 8; ++j) {
            float f = bf2f((unsigned short)v1[j]) * scale * w[(t + 256) * 8 + j];
            v1[j] = (short)f2bf(f);
        }
        reinterpret_cast<short8*>(p)[t + 256] = v1;
    }
}

// ---------------- NT GEMM: C = A(MxK) * B(NxK)^T, 128x128 tile, BK=32 (m97 structure) ----------------
template <int BF16OUT>
__global__ __launch_bounds__(256) void gemm_bt(const unsigned short* __restrict__ A,
                                               const unsigned short* __restrict__ Bm,
                                               unsigned short* __restrict__ Cb,
                                               float* __restrict__ Cf,
                                               const float* __restrict__ bias,
                                               int M, int N, int K, int MStore) {
    const int t = threadIdx.x;
    const int w = t >> 6, l = t & 63;
    const int lq = l & 15, lh = l >> 4;
    const int m0 = blockIdx.y * 128, n0 = blockIdx.x * 128;
    const int wr = w >> 1, wc = w & 1;

    __shared__ unsigned short sA[128 * 32];
    __shared__ unsigned short sB[128 * 32];

    const f32x4 fz = {0.f, 0.f, 0.f, 0.f};
    f32x4 acc[4][4];
#pragma unroll
    for (int i = 0; i < 4; ++i)
#pragma unroll
        for (int j = 0; j < 4; ++j) acc[i][j] = fz;

    const unsigned short* Abase = A + (long)m0 * K;
    const unsigned short* Bbase = Bm + (long)n0 * K;

    for (int k0 = 0; k0 < K; k0 += 32) {
        __syncthreads();
#pragma unroll
        for (int i = 0; i < 2; ++i) {
            int c = i * 256 + t;
            int row = c >> 2, slot = c & 3;         // 4 x 16B per 64B row
            gload_lds16(Abase + (long)row * K + k0 + slot * 8, (char*)sA + c * 16);
            gload_lds16(Bbase + (long)row * K + k0 + slot * 8, (char*)sB + c * 16);
        }
        __syncthreads();

        bf16x8 av[4], bv[4];
#pragma unroll
        for (int i = 0; i < 4; ++i) {
            int row = wr * 64 + i * 16 + lq;
            av[i] = *reinterpret_cast<const bf16x8*>(sA + row * 32 + lh * 8);
        }
#pragma unroll
        for (int j = 0; j < 4; ++j) {
            int row = wc * 64 + j * 16 + lq;
            bv[j] = *reinterpret_cast<const bf16x8*>(sB + row * 32 + lh * 8);
        }
#pragma unroll
        for (int i = 0; i < 4; ++i)
#pragma unroll
            for (int j = 0; j < 4; ++j)
                acc[i][j] = __builtin_amdgcn_mfma_f32_16x16x32_bf16(av[i], bv[j], acc[i][j], 0, 0, 0);
    }

#pragma unroll
    for (int i = 0; i < 4; ++i) {
#pragma unroll
        for (int r = 0; r < 4; ++r) {
            int grow = m0 + wr * 64 + i * 16 + lh * 4 + r;   // C/D: row=(l>>4)*4+reg
            if (grow >= MStore) continue;
#pragma unroll
            for (int j = 0; j < 4; ++j) {
                int gcol = n0 + wc * 64 + j * 16 + lq;       // C/D: col=lane&15
                float v = acc[i][j][r];
                if (BF16OUT)
                    Cb[(long)grow * N + gcol] = f2bf(v);
                else
                    Cf[(long)grow * N + gcol] = v + bias[gcol];
            }
        }
    }
}

// ---------------- flash attention: 64 q-rows/block (4 waves x 16), KV tile = 32 ----------------
__global__ __launch_bounds__(256) void attn_fwd(const unsigned short* __restrict__ qkv,
                                                unsigned short* __restrict__ outb) {
    const int qt = blockIdx.x, h = blockIdx.y, b = blockIdx.z;
    const int t = threadIdx.x, w = t >> 6, l = t & 63;
    const int lq = l & 15, lh = l >> 4;

    __shared__ unsigned short sK[32 * 128];     // [key][d], 16B slots XOR-swizzled via source
    __shared__ unsigned short sV[128 * 32];     // [d][key], slot-swizzled
    __shared__ unsigned short sP[4][16 * 32];   // per-wave P tile

    const int q0 = qt * 64 + w * 16;
    int qrow = q0 + lq; if (qrow > N_ - 1) qrow = N_ - 1;   // clamp; rows >= N_ never stored
    const unsigned short* qptr = qkv + (long)(b * N_ + qrow) * NQKV + h * D_;
    bf16x8 qf[4];
#pragma unroll
    for (int ds = 0; ds < 4; ++ds)
        qf[ds] = *reinterpret_cast<const bf16x8*>(qptr + ds * 32 + lh * 8);

    const f32x4 fz = {0.f, 0.f, 0.f, 0.f};
    f32x4 o[8];
#pragma unroll
    for (int nf = 0; nf < 8; ++nf) o[nf] = fz;
    float mreg[4] = {-1e30f, -1e30f, -1e30f, -1e30f};
    float lreg[4] = {0.f, 0.f, 0.f, 0.f};
    const float scale = 0.08838834764831845f;   // 1/sqrt(128)

    unsigned short* sPw = sP[w];

    for (int kt = 0; kt < 33; ++kt) {
        const int kb0 = kt * 32;
        __syncthreads();
        // stage K: linear LDS dest, swizzle applied to global source slot
#pragma unroll
        for (int i = 0; i < 2; ++i) {
            int c = i * 256 + t;
            int krow = c >> 4, slot = c & 15;
            int key = kb0 + krow; if (key > N_ - 1) key = N_ - 1;
            int sg = slot ^ (krow & 7);
            gload_lds16(qkv + (long)(b * N_ + key) * NQKV + C_ + h * D_ + sg * 8,
                        (char*)sK + c * 16);
        }
        // stage V transposed (reg round-trip), slot-XOR swizzle on writes
        {
            int kk = t >> 3, dblk = t & 7;
            int key = kb0 + kk; if (key > N_ - 1) key = N_ - 1;
            const unsigned short* vsrc = qkv + (long)(b * N_ + key) * NQKV + 2 * C_ + h * D_ + dblk * 16;
            short8 v0 = *reinterpret_cast<const short8*>(vsrc);
            short8 v1 = *reinterpret_cast<const short8*>(vsrc + 8);
#pragma unroll
            for (int j = 0; j < 8; ++j) {
                int d0 = dblk * 16 + j, d1 = d0 + 8;
                sV[d0 * 32 + ((((kk >> 3) ^ (d0 & 3))) << 3) + (kk & 7)] = (unsigned short)v0[j];
                sV[d1 * 32 + ((((kk >> 3) ^ (d1 & 3))) << 3) + (kk & 7)] = (unsigned short)v1[j];
            }
        }
        __syncthreads();

        // S = Q K^T  (16 q-rows x 32 keys per wave)
        f32x4 s0 = fz, s1 = fz;
#pragma unroll
        for (int ds = 0; ds < 4; ++ds) {
            int sl0 = (ds * 4 + lh) ^ (lq & 7);
            bf16x8 k0 = *reinterpret_cast<const bf16x8*>(sK + lq * 128 + sl0 * 8);
            s0 = __builtin_amdgcn_mfma_f32_16x16x32_bf16(qf[ds], k0, s0, 0, 0, 0);
            int kk1 = 16 + lq;
            int sl1 = (ds * 4 + lh) ^ (kk1 & 7);
            bf16x8 k1 = *reinterpret_cast<const bf16x8*>(sK + kk1 * 128 + sl1 * 8);
            s1 = __builtin_amdgcn_mfma_f32_16x16x32_bf16(qf[ds], k1, s1, 0, 0, 0);
        }
        const bool va0 = (kb0 + lq) < N_;
        const bool va1 = (kb0 + 16 + lq) < N_;
#pragma unroll
        for (int r = 0; r < 4; ++r) {
            s0[r] = va0 ? s0[r] * scale : -1e30f;
            s1[r] = va1 ? s1[r] * scale : -1e30f;
        }
        // online softmax per q-row (rows = lh*4+r, cols across the 16-lane group)
#pragma unroll
        for (int r = 0; r < 4; ++r) {
            float mx = fmaxf(s0[r], s1[r]);
#pragma unroll
            for (int msk = 1; msk < 16; msk <<= 1) mx = fmaxf(mx, __shfl_xor(mx, msk));
            float mnew = fmaxf(mreg[r], mx);
            float corr = __expf(mreg[r] - mnew);
            float p0 = __expf(s0[r] - mnew);
            float p1 = __expf(s1[r] - mnew);
            float rs = p0 + p1;
#pragma unroll
            for (int msk = 1; msk < 16; msk <<= 1) rs += __shfl_xor(rs, msk);
            lreg[r] = lreg[r] * corr + rs;
            mreg[r] = mnew;
#pragma unroll
            for (int nf = 0; nf < 8; ++nf) o[nf][r] *= corr;
            int prow = lh * 4 + r;
            int c1 = 16 + lq;
            sPw[prow * 32 + ((((lq >> 3) ^ (prow & 3))) << 3) + (lq & 7)] = f2bf(p0);
            sPw[prow * 32 + ((((c1 >> 3) ^ (prow & 3))) << 3) + (c1 & 7)] = f2bf(p1);
        }
        // PV: o(16x128) += P(16x32) * V(32x128)
        bf16x8 pa = *reinterpret_cast<const bf16x8*>(sPw + lq * 32 + ((lh ^ (lq & 3)) << 3));
#pragma unroll
        for (int nf = 0; nf < 8; ++nf) {
            int d = nf * 16 + lq;
            bf16x8 vf = *reinterpret_cast<const bf16x8*>(sV + d * 32 + ((lh ^ (d & 3)) << 3));
            o[nf] = __builtin_amdgcn_mfma_f32_16x16x32_bf16(pa, vf, o[nf], 0, 0, 0);
        }
    }

#pragma unroll
    for (int r = 0; r < 4; ++r) {
        int qr = q0 + lh * 4 + r;
        if (qr >= N_) continue;
        float inv = 1.f / lreg[r];
        unsigned short* dst = outb + (long)(b * N_ + qr) * C_ + h * D_;
#pragma unroll
        for (int nf = 0; nf < 8; ++nf)
            dst[nf * 16 + lq] = f2bf(o[nf][r] * inv);
    }
}

extern "C" void kernel_launch(void* const* d_in, const int* in_sizes, int n_in,
                              void* d_out, int out_size, void* d_ws, size_t ws_size,
                              hipStream_t stream) {
    (void)in_sizes; (void)n_in; (void)out_size; (void)ws_size;
    const float* x   = (const float*)d_in[0];
    const float* wq  = (const float*)d_in[1];
    const float* qnw = (const float*)d_in[2];
    const float* knw = (const float*)d_in[3];
    const float* wp  = (const float*)d_in[4];
    const float* bp  = (const float*)d_in[5];
    float* out = (float*)d_out;

    // workspace layout (bf16 buffers), total ~348 MB
    unsigned short* xb    = (unsigned short*)d_ws;                 // M_PAD x C
    unsigned short* wqb   = xb   + (size_t)M_PAD * C_;             // NQKV x C
    unsigned short* wpb   = wqb  + (size_t)NQKV * C_;              // C x C
    unsigned short* qkvb  = wpb  + (size_t)C_ * C_;                // M_PAD x NQKV
    unsigned short* attnb = qkvb + (size_t)M_PAD * NQKV;           // M_PAD x C

    auto cvt = [&](const float* s, unsigned short* d, long nsrc, long ntot) {
        int blocks = (int)((ntot / 4 + 255) / 256);
        convert_pad<<<blocks, 256, 0, stream>>>(s, d, nsrc, ntot);
    };
    cvt(x,  xb,  (long)M_REAL * C_, (long)M_PAD * C_);
    cvt(wq, wqb, (long)NQKV * C_,   (long)NQKV * C_);
    cvt(wp, wpb, (long)C_ * C_,     (long)C_ * C_);
    cvt(x, attnb + (size_t)M_REAL * C_, 0, (long)(M_PAD - M_REAL) * C_);  // zero pad rows

    gemm_bt<1><<<dim3(NQKV / 128, M_PAD / 128), 256, 0, stream>>>(
        xb, wqb, qkvb, nullptr, nullptr, M_PAD, NQKV, C_, M_PAD);

    rmsnorm_qk<<<dim3(M_REAL, 2), 256, 0, stream>>>(qkvb, qnw, knw);

    attn_fwd<<<dim3(17, H_, B_), 256, 0, stream>>>(qkvb, attnb);

    gemm_bt<0><<<dim3(C_ / 128, M_PAD / 128), 256, 0, stream>>>(
        attnb, wpb, nullptr, out, bp, M_PAD, C_, C_, M_REAL);
}